// Round 5
// baseline (340.486 us; speedup 1.0000x reference)
//
#include <hip/hip_runtime.h>

// AdaptiveAttentionLoss: focal-weighted CE (C=2, beta=2) + segmented mean over
// G=4096 groups + mean over present groups.
// R2-R4: libm log1pf/expf -> native v_exp/v_log/v_rcp (~15 VALU/sample),
//        occupancy 16->32 waves/CU, lane-contiguous loads, fused finalize.

#define G_GROUPS 4096
#define ACC_BLOCKS 1024
#define ACC_THREADS 512

__global__ void aal_zero_kernel(float* __restrict__ acc) {
    int i = blockIdx.x * blockDim.x + threadIdx.x;
    if (i < 2 * G_GROUPS + 1) acc[i] = 0.0f;   // gsum, gcnt, done-counter
}

// 32 KiB LDS/block, 512 thr = 8 waves -> 4 blocks/CU = 32 waves/CU.
__global__ __launch_bounds__(ACC_THREADS, 8) void aal_accum_kernel(
    const float4* __restrict__ x2,     // [N/2]: {x[2t][0],x[2t][1],x[2t+1][0],x[2t+1][1]}
    const int2*  __restrict__ idx2,    // [N/2]
    const int2*  __restrict__ lab2,    // [N/2]
    float* __restrict__ gsum,          // [G]
    float* __restrict__ gcnt,          // [G]
    unsigned* __restrict__ done_ctr,   // [1]
    float* __restrict__ out,
    int nvec2)                         // N/2
{
    __shared__ float    s_sum[G_GROUPS];
    __shared__ unsigned s_cnt[G_GROUPS];
    for (int i = threadIdx.x; i < G_GROUPS; i += ACC_THREADS) {
        s_sum[i] = 0.0f;
        s_cnt[i] = 0u;
    }
    __syncthreads();

    const int tid    = blockIdx.x * ACC_THREADS + threadIdx.x;
    const int stride = gridDim.x * ACC_THREADS;

    for (int v = tid; v < nvec2; v += stride) {
        float4 xv = x2[v];     // perfectly coalesced: 16 B/lane contiguous
        int2   iv = idx2[v];
        int2   lv = lab2[v];

        float xA[2] = {xv.x, xv.z};    // class-0 logits of the 2 samples
        float xB[2] = {xv.y, xv.w};    // class-1 logits
        int   ii[2] = {iv.x, iv.y};
        int   ll[2] = {lv.x, lv.y};

#pragma unroll
        for (int s = 0; s < 2; ++s) {  // static indexing only (rule #20)
            float xt = ll[s] ? xB[s] : xA[s];
            float xo = ll[s] ? xA[s] : xB[s];
            float d  = xo - xt;                 // ce = softplus(d)
            float t  = __expf(-fabsf(d));       // v_exp_f32 path, t in (0,1]
            float denom = 1.0f + t;
            float ce = fmaxf(d, 0.0f) + __logf(denom);
            // p = 1/(1+e^d): d>=0 -> t/(1+t); d<0 -> 1/(1+t)
            float r  = __builtin_amdgcn_rcpf(denom);
            float p  = (d >= 0.0f ? t : 1.0f) * r;
            float w  = fmaf(-p, p, 1.0f);       // 1 - p^2  (beta=2)
            float val = w * ce;
            atomicAdd(&s_sum[ii[s]], val);      // ds_add_f32
            atomicAdd(&s_cnt[ii[s]], 1u);       // ds_add_u32
        }
    }
    __syncthreads();

    // One global atomic pair per present group per block (G12).
    for (int i = threadIdx.x; i < G_GROUPS; i += ACC_THREADS) {
        unsigned c = s_cnt[i];
        if (c) {
            atomicAdd(&gsum[i], s_sum[i]);
            atomicAdd(&gcnt[i], (float)c);   // exact: counts <= 2^24
        }
    }

    // ---- fused finalize: last block to finish reduces the group means ----
    __shared__ unsigned s_isLast;
    if (threadIdx.x == 0) {
        __threadfence();                          // flush atomics visible first
        unsigned old = atomicAdd(done_ctr, 1u);   // device-scope
        s_isLast = (old == (unsigned)(gridDim.x - 1)) ? 1u : 0u;
    }
    __syncthreads();
    if (!s_isLast) return;

    // Read back through the SAME coherent path as the writes (atomic RMW+0):
    // safe across non-coherent per-XCD L2s (G16).
    float msum = 0.0f, pres = 0.0f;
    for (int i = threadIdx.x; i < G_GROUPS; i += ACC_THREADS) {
        float c = atomicAdd(&gcnt[i], 0.0f);
        if (c > 0.0f) {
            float ssum = atomicAdd(&gsum[i], 0.0f);
            msum += ssum / c;
            pres += 1.0f;
        }
    }
    float* s_red  = s_sum;               // reuse LDS (synced above)
    float* s_red2 = (float*)s_cnt;
    s_red[threadIdx.x]  = msum;
    s_red2[threadIdx.x] = pres;
    __syncthreads();
    for (int o = ACC_THREADS / 2; o > 0; o >>= 1) {
        if (threadIdx.x < (unsigned)o) {
            s_red[threadIdx.x]  += s_red[threadIdx.x + o];
            s_red2[threadIdx.x] += s_red2[threadIdx.x + o];
        }
        __syncthreads();
    }
    if (threadIdx.x == 0) out[0] = s_red[0] / s_red2[0];
}

extern "C" void kernel_launch(void* const* d_in, const int* in_sizes, int n_in,
                              void* d_out, int out_size, void* d_ws, size_t ws_size,
                              hipStream_t stream) {
    const float4* x2   = (const float4*)d_in[0];
    const int2*   idx2 = (const int2*)d_in[1];
    const int2*   lab2 = (const int2*)d_in[2];
    const int N = in_sizes[1];          // index element count == N samples
    const int nvec2 = N / 2;            // N = 2^24, divisible by 2

    float*    gsum     = (float*)d_ws;            // [G]
    float*    gcnt     = gsum + G_GROUPS;         // [G]
    unsigned* done_ctr = (unsigned*)(gcnt + G_GROUPS);  // [1]
    float*    out      = (float*)d_out;

    aal_zero_kernel<<<(2 * G_GROUPS + 1 + 255) / 256, 256, 0, stream>>>(gsum);
    aal_accum_kernel<<<ACC_BLOCKS, ACC_THREADS, 0, stream>>>(
        x2, idx2, lab2, gsum, gcnt, done_ctr, out, nvec2);
}

// Round 6
// 312.211 us; speedup vs baseline: 1.0906x; 1.0906x over previous
//
#include <hip/hip_runtime.h>

// AdaptiveAttentionLoss: focal-weighted CE (C=2, beta=2) + segmented mean over
// G=4096 groups + mean over present groups.
// R6: post-mortem of R2 regression (167us vs R1 111us): VGPR starvation
// (launch_bounds(512,8) -> 12 VGPRs) + halved MLP + doubled flush atomics.
// Fix: 1024-thr blocks grid=512 (exact 2 blocks/CU fill), 4 lane-contiguous
// vec2-units per iteration (12 loads in flight, 128 B/lane/iter), flush back
// to 4.2M atomics. Keep native trans + fused last-block finalize.

#define G_GROUPS 4096
#define ACC_THREADS 1024
#define ACC_BLOCKS 512

__global__ void aal_zero_kernel(float* __restrict__ acc) {
    int i = blockIdx.x * blockDim.x + threadIdx.x;
    if (i < 2 * G_GROUPS + 1) acc[i] = 0.0f;   // gsum, gcnt, done-counter
}

// Per-sample math: ce = softplus(d), p = sigmoid(-d), w = 1-p^2, val = w*ce.
__device__ __forceinline__ void aal_sample(float xA, float xB, int lab,
                                           float* s_sum, unsigned* s_cnt,
                                           int grp) {
    float xt = lab ? xB : xA;
    float xo = lab ? xA : xB;
    float d  = xo - xt;
    float t  = __expf(-fabsf(d));        // v_exp_f32, t in (0,1]
    float denom = 1.0f + t;
    float ce = fmaxf(d, 0.0f) + __logf(denom);
    float r  = __builtin_amdgcn_rcpf(denom);
    float p  = (d >= 0.0f ? t : 1.0f) * r;
    float w  = fmaf(-p, p, 1.0f);        // 1 - p^2 (beta=2)
    atomicAdd(&s_sum[grp], w * ce);      // ds_add_f32
    atomicAdd(&s_cnt[grp], 1u);         // ds_add_u32
}

// 32.5 KiB LDS/block, 1024 thr = 16 waves; 2 blocks/CU -> 32 waves/CU.
__global__ __launch_bounds__(ACC_THREADS, 8) void aal_accum_kernel(
    const float4* __restrict__ x2,     // [N/2]: 2 samples per float4
    const int2*  __restrict__ idx2,    // [N/2]
    const int2*  __restrict__ lab2,    // [N/2]
    float* __restrict__ gsum,          // [G]
    float* __restrict__ gcnt,          // [G]
    unsigned* __restrict__ done_ctr,   // [1]
    float* __restrict__ out,
    int nvec2)                         // N/2
{
    __shared__ float    s_sum[G_GROUPS];
    __shared__ unsigned s_cnt[G_GROUPS];
    for (int i = threadIdx.x; i < G_GROUPS; i += ACC_THREADS) {
        s_sum[i] = 0.0f;
        s_cnt[i] = 0u;
    }
    __syncthreads();

    const int tid    = blockIdx.x * ACC_THREADS + threadIdx.x;
    const int stride = gridDim.x * ACC_THREADS;   // 524288

    int v = tid;
    // Main loop: 4 vec2-units per iteration, every load lane-contiguous.
    for (; v + 3 * stride < nvec2; v += 4 * stride) {
        // Issue all 12 independent loads first (MLP: 128 B/lane in flight).
        float4 xv0 = x2[v];
        float4 xv1 = x2[v +     stride];
        float4 xv2 = x2[v + 2 * stride];
        float4 xv3 = x2[v + 3 * stride];
        int2 iv0 = idx2[v];
        int2 iv1 = idx2[v +     stride];
        int2 iv2 = idx2[v + 2 * stride];
        int2 iv3 = idx2[v + 3 * stride];
        int2 lv0 = lab2[v];
        int2 lv1 = lab2[v +     stride];
        int2 lv2 = lab2[v + 2 * stride];
        int2 lv3 = lab2[v + 3 * stride];

        aal_sample(xv0.x, xv0.y, lv0.x, s_sum, s_cnt, iv0.x);
        aal_sample(xv0.z, xv0.w, lv0.y, s_sum, s_cnt, iv0.y);
        aal_sample(xv1.x, xv1.y, lv1.x, s_sum, s_cnt, iv1.x);
        aal_sample(xv1.z, xv1.w, lv1.y, s_sum, s_cnt, iv1.y);
        aal_sample(xv2.x, xv2.y, lv2.x, s_sum, s_cnt, iv2.x);
        aal_sample(xv2.z, xv2.w, lv2.y, s_sum, s_cnt, iv2.y);
        aal_sample(xv3.x, xv3.y, lv3.x, s_sum, s_cnt, iv3.x);
        aal_sample(xv3.z, xv3.w, lv3.y, s_sum, s_cnt, iv3.y);
    }
    // Remainder (empty for N=2^24 with this grid, kept for generality).
    for (; v < nvec2; v += stride) {
        float4 xv = x2[v];
        int2 iv = idx2[v];
        int2 lv = lab2[v];
        aal_sample(xv.x, xv.y, lv.x, s_sum, s_cnt, iv.x);
        aal_sample(xv.z, xv.w, lv.y, s_sum, s_cnt, iv.y);
    }
    __syncthreads();

    // One global atomic pair per present group per block (G12): 4.2M total.
    for (int i = threadIdx.x; i < G_GROUPS; i += ACC_THREADS) {
        unsigned c = s_cnt[i];
        if (c) {
            atomicAdd(&gsum[i], s_sum[i]);
            atomicAdd(&gcnt[i], (float)c);   // exact: counts <= 2^24
        }
    }

    // ---- fused finalize: last block to finish reduces the group means ----
    __shared__ unsigned s_isLast;
    if (threadIdx.x == 0) {
        __threadfence();                          // flush atomics visible first
        unsigned old = atomicAdd(done_ctr, 1u);   // device-scope
        s_isLast = (old == (unsigned)(gridDim.x - 1)) ? 1u : 0u;
    }
    __syncthreads();
    if (!s_isLast) return;

    // Read back through the SAME coherent path as the writes (atomic RMW+0):
    // safe across non-coherent per-XCD L2s (G16).
    float msum = 0.0f, pres = 0.0f;
    for (int i = threadIdx.x; i < G_GROUPS; i += ACC_THREADS) {
        float c = atomicAdd(&gcnt[i], 0.0f);
        if (c > 0.0f) {
            float ssum = atomicAdd(&gsum[i], 0.0f);
            msum += ssum / c;
            pres += 1.0f;
        }
    }
    float* s_red  = s_sum;               // reuse LDS (synced above)
    float* s_red2 = (float*)s_cnt;
    s_red[threadIdx.x]  = msum;
    s_red2[threadIdx.x] = pres;
    __syncthreads();
    for (int o = ACC_THREADS / 2; o > 0; o >>= 1) {
        if (threadIdx.x < (unsigned)o) {
            s_red[threadIdx.x]  += s_red[threadIdx.x + o];
            s_red2[threadIdx.x] += s_red2[threadIdx.x + o];
        }
        __syncthreads();
    }
    if (threadIdx.x == 0) out[0] = s_red[0] / s_red2[0];
}

extern "C" void kernel_launch(void* const* d_in, const int* in_sizes, int n_in,
                              void* d_out, int out_size, void* d_ws, size_t ws_size,
                              hipStream_t stream) {
    const float4* x2   = (const float4*)d_in[0];
    const int2*   idx2 = (const int2*)d_in[1];
    const int2*   lab2 = (const int2*)d_in[2];
    const int N = in_sizes[1];          // index element count == N samples
    const int nvec2 = N / 2;            // N = 2^24, divisible by 2

    float*    gsum     = (float*)d_ws;            // [G]
    float*    gcnt     = gsum + G_GROUPS;         // [G]
    unsigned* done_ctr = (unsigned*)(gcnt + G_GROUPS);  // [1]
    float*    out      = (float*)d_out;

    aal_zero_kernel<<<(2 * G_GROUPS + 1 + 255) / 256, 256, 0, stream>>>(gsum);
    aal_accum_kernel<<<ACC_BLOCKS, ACC_THREADS, 0, stream>>>(
        x2, idx2, lab2, gsum, gcnt, done_ctr, out, nvec2);
}